// Round 1
// baseline (63083.301 us; speedup 1.0000x reference)
//
#include <hip/hip_runtime.h>
#include <math.h>

#define NBLK 256
#define NTHR 256
#define HB 64      // batches per half
#define T_ 512
#define U_ 128
#define N_ 80
#define H_ 512
#define M_ 10
#define KTOT 595   // K order: [h 0..511][w 0..79][x 0..2]

// 16 FMAs: 4 batches (iv lanes) x 4 cols (wv lanes)
#define FMA16(iv, wv) do { \
    acc[0][0] = fmaf((iv).x, (wv).x, acc[0][0]); acc[0][1] = fmaf((iv).x, (wv).y, acc[0][1]); \
    acc[0][2] = fmaf((iv).x, (wv).z, acc[0][2]); acc[0][3] = fmaf((iv).x, (wv).w, acc[0][3]); \
    acc[1][0] = fmaf((iv).y, (wv).x, acc[1][0]); acc[1][1] = fmaf((iv).y, (wv).y, acc[1][1]); \
    acc[1][2] = fmaf((iv).y, (wv).z, acc[1][2]); acc[1][3] = fmaf((iv).y, (wv).w, acc[1][3]); \
    acc[2][0] = fmaf((iv).z, (wv).x, acc[2][0]); acc[2][1] = fmaf((iv).z, (wv).y, acc[2][1]); \
    acc[2][2] = fmaf((iv).z, (wv).z, acc[2][2]); acc[2][3] = fmaf((iv).z, (wv).w, acc[2][3]); \
    acc[3][0] = fmaf((iv).w, (wv).x, acc[3][0]); acc[3][1] = fmaf((iv).w, (wv).y, acc[3][1]); \
    acc[3][2] = fmaf((iv).w, (wv).z, acc[3][2]); acc[3][3] = fmaf((iv).w, (wv).w, acc[3][3]); \
} while (0)

__global__ __launch_bounds__(NTHR, 1) void rnn_kernel(
    const float* __restrict__ strokes, const float* __restrict__ trans,
    const float* __restrict__ Wx, const float* __restrict__ Wh,
    const float* __restrict__ bias, const float* __restrict__ Wd,
    const float* __restrict__ bd, float* __restrict__ out,
    float* __restrict__ hbuf, float* __restrict__ wbufT, float* __restrict__ hT,
    unsigned* __restrict__ cnt) {

    // LDS ~45 KB: weight slice stays resident; input staging now via registers
    __shared__ __align__(16) float Wl[KTOT * 16];      // 38080 B weight slice, permuted K order
    __shared__ __align__(16) float zbuf[64 * 20];      // 5120 B z / reused as h-column in stage B
    __shared__ float cst[256];                         // c-state [b][jl]
    __shared__ float kap[M_];
    __shared__ float yl[30];
    __shared__ float wf[U_ + 1];

    const int tid  = threadIdx.x;
    const int bid  = blockIdx.x;
    const int half = bid >> 7;     // batch half
    const int hs   = bid & 127;    // h-slice: h-units hs*4..hs*4+3
    const int lane = tid & 63;
    const int rw   = tid >> 6;     // wave id = col-group (gate)
    const int bg4  = lane & 15;    // batch group of 4
    const int ks   = lane >> 4;    // K-split 4 (lane bits 4-5)
    const int cg4  = rw * 4;
    const int bg44 = bg4 * 4;
    (void)bg4;

    unsigned* hcnt = cnt + half * 32;        // h-ready: +128 per step
    unsigned* wcnt = cnt + 64 + half * 32;   // w-ready: +64 per step
    float* wT_half = wbufT + half * (N_ * HB);

    // ---- init: weights (permuted K), zero state ----
    for (int idx = tid; idx < KTOT * 16; idx += NTHR) {
        int kk = idx >> 4, cc = idx & 15;
        int col = (cc >> 2) * 512 + hs * 4 + (cc & 3);   // gate*512 + h-unit
        float v;
        if (kk < 512)      v = Wh[kk * 2048 + col];
        else if (kk < 592) v = Wx[(3 + kk - 512) * 2048 + col];
        else               v = Wx[(kk - 592) * 2048 + col];
        Wl[idx] = v;
    }
    for (int i = tid; i < 256; i += NTHR) cst[i] = 0.f;
    if (tid < M_) kap[tid] = 0.f;
    for (int i = bid * NTHR + tid; i < 2 * H_ * HB + 2 * N_ * HB; i += NBLK * NTHR) {
        if (i < 2 * H_ * HB) hbuf[i] = 0.f;            // parity-0 h = 0
        else wbufT[i - 2 * H_ * HB] = 0.f;             // w_{-1} = 0
    }
    __syncthreads();
    if (tid == 0) {                                    // one-time flat init barrier
        __threadfence();
        atomicAdd(&cnt[128], 1u);
        while (__hip_atomic_load(&cnt[128], __ATOMIC_RELAXED, __HIP_MEMORY_SCOPE_AGENT) < (unsigned)NBLK)
            __builtin_amdgcn_s_sleep(1);
        __threadfence();
    }
    __syncthreads();

    const bool isB = (hs & 1) == 0;                    // 64 stage-B blocks per half
    const int  bB  = half * HB + (hs >> 1);            // its batch

    for (int t = 0; t < T_; ++t) {
        const float* hR = hbuf + ((t & 1) * 2 + half) * (H_ * HB);
        float*       hW = hbuf + (((t + 1) & 1) * 2 + half) * (H_ * HB);

        // ---- wait h_{t-1} (per-half) ----
        if (tid == 0) {
            while (__hip_atomic_load(hcnt, __ATOMIC_RELAXED, __HIP_MEMORY_SCOPE_AGENT) < 128u * (unsigned)t)
                __builtin_amdgcn_s_sleep(1);
            __threadfence();
        }
        __syncthreads();

        float acc[4][4];
        #pragma unroll
        for (int a = 0; a < 4; ++a)
            #pragma unroll
            for (int b2 = 0; b2 < 4; ++b2) acc[a][b2] = 0.f;

        const float* hA  = hR + ks * 64 + bg44;        // row k=4i+ks -> +i*256 floats
        const float* wlA = &Wl[ks * 16 + cg4];         // same row in weight slice

        // ---- h part: k = 0..511, register double-buffered, NO barriers ----
        // 8 groups of 16 rows; load group g+1 while computing group g.
        {
            float4 va[16], vb[16];
            #pragma unroll
            for (int r = 0; r < 16; ++r) va[r] = *(const float4*)(hA + r * 256);
            for (int g = 0; g < 6; g += 2) {
                #pragma unroll
                for (int r = 0; r < 16; ++r) vb[r] = *(const float4*)(hA + ((g + 1) * 16 + r) * 256);
                #pragma unroll
                for (int r = 0; r < 16; ++r) { float4 wv = *(const float4*)(wlA + (g * 16 + r) * 64); FMA16(va[r], wv); }
                #pragma unroll
                for (int r = 0; r < 16; ++r) va[r] = *(const float4*)(hA + ((g + 2) * 16 + r) * 256);
                #pragma unroll
                for (int r = 0; r < 16; ++r) { float4 wv = *(const float4*)(wlA + ((g + 1) * 16 + r) * 64); FMA16(vb[r], wv); }
            }
            // tail: groups 6 (in va) and 7
            #pragma unroll
            for (int r = 0; r < 16; ++r) vb[r] = *(const float4*)(hA + (112 + r) * 256);
            #pragma unroll
            for (int r = 0; r < 16; ++r) { float4 wv = *(const float4*)(wlA + (96 + r) * 64); FMA16(va[r], wv); }
            #pragma unroll
            for (int r = 0; r < 16; ++r) { float4 wv = *(const float4*)(wlA + (112 + r) * 64); FMA16(vb[r], wv); }
        }

        // ---- wait w_{t-1}, then w part: k = 512+4i+ks, i = 0..19 ----
        if (tid == 0) {
            while (__hip_atomic_load(wcnt, __ATOMIC_RELAXED, __HIP_MEMORY_SCOPE_AGENT) < 64u * (unsigned)t)
                __builtin_amdgcn_s_sleep(1);
            __threadfence();
        }
        __syncthreads();

        {
            const float* wA = wT_half + ks * 64 + bg44;
            float4 wva[20];
            #pragma unroll
            for (int r = 0; r < 20; ++r) wva[r] = *(const float4*)(wA + r * 256);
            #pragma unroll
            for (int r = 0; r < 20; ++r) { float4 wv = *(const float4*)(wlA + (128 + r) * 64); FMA16(wva[r], wv); }
        }

        // ---- x part (k = 592..594, row r = ks; last, matching original per-thread order) ----
        if (ks < 3) {
            const float* sp = strokes + (size_t)(half * HB + bg44) * (T_ * 3) + t * 3 + ks;
            float4 xv;
            xv.x = sp[0];
            xv.y = sp[T_ * 3];
            xv.z = sp[2 * (T_ * 3)];
            xv.w = sp[3 * (T_ * 3)];
            float4 wv = *(const float4*)(&Wl[(592 + ks) * 16 + cg4]);
            FMA16(xv, wv);
        }

        // ---- cross-K reduce (lane bits 4,5) + stash z ----
        #pragma unroll
        for (int bb = 0; bb < 4; ++bb) {
            #pragma unroll
            for (int cc2 = 0; cc2 < 4; ++cc2) {
                float v = acc[bb][cc2];
                v += __shfl_xor(v, 16, 64);
                v += __shfl_xor(v, 32, 64);
                acc[bb][cc2] = v;
            }
            if (ks == 0)
                *(float4*)&zbuf[(bg44 + bb) * 20 + cg4] =
                    make_float4(acc[bb][0], acc[bb][1], acc[bb][2], acc[bb][3]);
        }
        __syncthreads();

        // ---- LSTM pointwise: thread = (b, jl) ----
        {
            int b = tid & 63, jl = tid >> 6;
            int colb = hs * 4 + jl;
            float zi = zbuf[b * 20 + 0  + jl] + bias[colb];
            float zf = zbuf[b * 20 + 4  + jl] + bias[512 + colb];
            float zg = zbuf[b * 20 + 8  + jl] + bias[1024 + colb];
            float zo = zbuf[b * 20 + 12 + jl] + bias[1536 + colb];
            float co = cst[b * 4 + jl];
            float si = 1.f / (1.f + expf(-zi));
            float sf = 1.f / (1.f + expf(-zf));
            float so = 1.f / (1.f + expf(-zo));
            float cn = sf * co + si * tanhf(zg);
            float hn = so * tanhf(cn);
            cst[b * 4 + jl] = cn;
            hW[colb * 64 + b] = hn;                             // [j][b] for GEMM consumers
            hT[(size_t)(half * HB + b) * 512 + colb] = hn;      // [b][j] for stage B
        }
        __syncthreads();
        if (tid == 0) { __threadfence(); atomicAdd(hcnt, 1u); }  // release h_t

        // ---- stage B: attention, overlapped with other blocks' next GEMM ----
        if (isB) {
            if (tid == 0) {
                while (__hip_atomic_load(hcnt, __ATOMIC_RELAXED, __HIP_MEMORY_SCOPE_AGENT) < 128u * (unsigned)(t + 1))
                    __builtin_amdgcn_s_sleep(1);
                __threadfence();
            }
            __syncthreads();
            if (tid < 128)   // coalesced 2KB h-column load
                ((float4*)zbuf)[tid] = ((const float4*)(hT + (size_t)bB * 512))[tid];
            __syncthreads();
            if (tid < 240) {                       // y = h @ Wd : 30 cols x 8 segs
                int col = tid >> 3, seg = tid & 7;
                const float* hp = zbuf + seg * 64;
                const float* wdp = Wd + (size_t)seg * 64 * 30 + col;
                float s = 0.f;
                #pragma unroll 8
                for (int jj = 0; jj < 64; ++jj) s = fmaf(hp[jj], wdp[jj * 30], s);
                s += __shfl_down(s, 4, 8);
                s += __shfl_down(s, 2, 8);
                s += __shfl_down(s, 1, 8);
                if (seg == 0) yl[col] = s;
            }
            __syncthreads();
            if (tid < 30) {
                float e = expf(yl[tid] + bd[tid]);
                yl[tid] = e;
                if (tid >= 20) kap[tid - 20] += e;
            }
            __syncthreads();
            if (tid <= U_) {
                float u = (float)tid, s = 0.f;
                #pragma unroll
                for (int m = 0; m < M_; ++m) {
                    float d = kap[m] - u;
                    s += yl[m] * expf(-yl[10 + m] * d * d);
                }
                wf[tid] = s;
            }
            __syncthreads();
            float* op = out + ((size_t)bB * T_ + t) * 593;
            if (tid < 64) {                        // barrier-free in-wave argmax tournament
                float v = wf[tid]; int ii = tid;   // (identical bracket + strict-> tie rule)
                float v2 = wf[tid + 64];
                if (v2 > v) { v = v2; ii = tid + 64; }
                #pragma unroll
                for (int s2 = 32; s2 >= 1; s2 >>= 1) {
                    float ov = __shfl_down(v, s2, 64);
                    int   oi = __shfl_down(ii, s2, 64);
                    if (ov > v) { v = ov; ii = oi; }
                }
                if (tid == 0) {
                    if (wf[128] > v) ii = 128;     // fold index 128 (strict >)
                    op[592] = (float)ii;
                }
            }
            for (int j = tid; j < H_; j += NTHR) op[j] = zbuf[j];   // coalesced h out
            if (tid < N_) {                        // w = wfull[:128] @ trans[b]
                const float* tp = trans + (size_t)bB * (U_ * N_) + tid;
                float s = 0.f;
                #pragma unroll 4
                for (int u = 0; u < U_; ++u) s = fmaf(wf[u], tp[u * N_], s);
                op[512 + tid] = s;
                wT_half[tid * 64 + (bB & 63)] = s;
            }
            __syncthreads();
            if (tid == 0) { __threadfence(); atomicAdd(wcnt, 1u); }  // release w_t
        }
    }
}

extern "C" void kernel_launch(void* const* d_in, const int* in_sizes, int n_in,
                              void* d_out, int out_size, void* d_ws, size_t ws_size,
                              hipStream_t stream) {
    const float* strokes = (const float*)d_in[0];
    const float* trans   = (const float*)d_in[1];
    // d_in[2] = enumerated (arange, recomputed in-kernel)
    const float* Wx      = (const float*)d_in[3];
    const float* Wh      = (const float*)d_in[4];
    const float* bias    = (const float*)d_in[5];
    const float* Wd      = (const float*)d_in[6];
    const float* bd      = (const float*)d_in[7];
    float* out = (float*)d_out;

    unsigned* cnt = (unsigned*)d_ws;                       // 4 KB counters
    float* hbuf  = (float*)((char*)d_ws + 4096);           // [par][half][512][64] 512 KB
    float* wbufT = hbuf + 2 * 2 * H_ * HB;                 // [half][80][64] 40 KB
    float* hT    = wbufT + 2 * N_ * HB;                    // [128][512] 256 KB

    hipMemsetAsync(d_ws, 0, 4096, stream);                 // reset counters (ws is poisoned)
    hipLaunchKernelGGL(rnn_kernel, dim3(NBLK), dim3(NTHR), 0, stream,
                       strokes, trans, Wx, Wh, bias, Wd, bd, out, hbuf, wbufT, hT, cnt);
}

// Round 2
// 22695.390 us; speedup vs baseline: 2.7796x; 2.7796x over previous
//
#include <hip/hip_runtime.h>
#include <math.h>

#define NBLK 256
#define NTHR 256
#define HB 64      // batches per half
#define T_ 512
#define U_ 128
#define N_ 80
#define H_ 512
#define M_ 10
#define KTOT 595   // K order: [h 0..511][w 0..79][x 0..2]

typedef __attribute__((address_space(1))) const unsigned int* gp1_t;
typedef __attribute__((address_space(3))) unsigned int* lp3_t;
// width-16 global->LDS DMA: lane i writes ldsbase + i*16, reads gptr + i*16
#define GLOAD16(gp, lp) __builtin_amdgcn_global_load_lds((gp1_t)(gp), (lp3_t)(lp), 16, 0, 0)

__device__ __forceinline__ unsigned ldA(const unsigned* p) {
    return __hip_atomic_load(p, __ATOMIC_RELAXED, __HIP_MEMORY_SCOPE_AGENT);
}
__device__ __forceinline__ void stRel(unsigned* p, unsigned v) {
    __hip_atomic_store(p, v, __ATOMIC_RELEASE, __HIP_MEMORY_SCOPE_AGENT);
}

__global__ __launch_bounds__(NTHR) void rnn_kernel(
    const float* __restrict__ strokes, const float* __restrict__ trans,
    const float* __restrict__ Wx, const float* __restrict__ Wh,
    const float* __restrict__ bias, const float* __restrict__ Wd,
    const float* __restrict__ bd, float* __restrict__ out,
    float* __restrict__ hbuf, float* __restrict__ wbufT, float* __restrict__ hT,
    unsigned* __restrict__ cnt) {

    // LDS ~61.4 KB (<64 KB static)
    __shared__ __align__(16) float Wl[KTOT * 16];      // 38080 B weight slice, permuted K order
    __shared__ __align__(16) float inpT[2][32 * 64];   // 16384 B dbuf input chunks [k][b]
    __shared__ __align__(16) float zbuf[64 * 20];      // 5120 B z / reused as h-column in stage B
    __shared__ float cst[256];                         // c-state [b][jl]
    __shared__ float kap[M_];
    __shared__ float yl[30];
    __shared__ float wf[U_ + 1];

    const int tid  = threadIdx.x;
    const int bid  = blockIdx.x;
    const int half = bid >> 7;     // batch half
    const int hs   = bid & 127;    // h-slice: h-units hs*4..hs*4+3
    const int lane = tid & 63;
    const int rw   = tid >> 6;     // wave id = col-group (gate)
    const int bg4  = lane & 15;    // batch group of 4
    const int ks   = lane >> 4;    // K-split 4 (lane bits 4-5)
    const int cg4  = rw * 4;
    const int bg44 = bg4 * 4;

    // per-block done-slots (no RMW fan-in): dn_h[half][128], dn_w[half][64]
    unsigned* dn_h = cnt + 256 + half * 128;
    unsigned* dn_w = cnt + 512 + half * 64;
    float* wT_half = wbufT + half * (N_ * HB);

    // ---- init: weights (permuted K), zero state ----
    for (int idx = tid; idx < KTOT * 16; idx += NTHR) {
        int kk = idx >> 4, cc = idx & 15;
        int col = (cc >> 2) * 512 + hs * 4 + (cc & 3);   // gate*512 + h-unit
        float v;
        if (kk < 512)      v = Wh[kk * 2048 + col];
        else if (kk < 592) v = Wx[(3 + kk - 512) * 2048 + col];
        else               v = Wx[(kk - 592) * 2048 + col];
        Wl[idx] = v;
    }
    for (int i = tid; i < 256; i += NTHR) cst[i] = 0.f;
    if (tid < M_) kap[tid] = 0.f;
    for (int i = bid * NTHR + tid; i < 2 * H_ * HB + 2 * N_ * HB; i += NBLK * NTHR) {
        if (i < 2 * H_ * HB) hbuf[i] = 0.f;            // parity-0 h = 0
        else wbufT[i - 2 * H_ * HB] = 0.f;             // w_{-1} = 0
    }
    __syncthreads();
    if (tid == 0) {                                    // one-time flat init barrier
        __threadfence();
        atomicAdd(&cnt[128], 1u);
        while (__hip_atomic_load(&cnt[128], __ATOMIC_RELAXED, __HIP_MEMORY_SCOPE_AGENT) < (unsigned)NBLK)
            __builtin_amdgcn_s_sleep(1);
        __threadfence();
    }
    __syncthreads();

    const bool isB = (hs & 1) == 0;                    // 64 stage-B blocks per half
    const int  bB  = half * HB + (hs >> 1);            // its batch

    for (int t = 0; t < T_; ++t) {
        const float* hR = hbuf + ((t & 1) * 2 + half) * (H_ * HB);
        float*       hW = hbuf + (((t + 1) & 1) * 2 + half) * (H_ * HB);

        // ---- wait h_{t-1}: all 128 producer blocks of this half at step >= t ----
        if (tid < 64) {
            const unsigned tgt = (unsigned)t;
            for (;;) {
                unsigned v0 = ldA(dn_h + tid);
                unsigned v1 = ldA(dn_h + 64 + tid);
                if (!__any((v0 < tgt) | (v1 < tgt))) break;
                __builtin_amdgcn_s_sleep(1);
            }
            __builtin_amdgcn_fence(__ATOMIC_ACQUIRE, "agent");
        }
        __syncthreads();

        float acc[4][4];
        #pragma unroll
        for (int a = 0; a < 4; ++a)
            #pragma unroll
            for (int b2 = 0; b2 < 4; ++b2) acc[a][b2] = 0.f;

        // stage chunk 0 (h rows 0..31): 2 DMA issues per wave, 4 rows each
        {
            const float* src = hR;
            float* dst = &inpT[0][0];
            GLOAD16(src + rw * 256 + lane * 4, dst + rw * 256);
            GLOAD16(src + (rw + 4) * 256 + lane * 4, dst + (rw + 4) * 256);
        }
        __syncthreads();

        for (int c = 0; c < 19; ++c) {
            if (c + 1 < 19) {
                if (c + 1 == 16) {        // w rows start: need w_{t-1}
                    if (tid < 64) {
                        const unsigned tgt = (unsigned)t;
                        for (;;) {
                            unsigned v0 = ldA(dn_w + tid);
                            if (!__any(v0 < tgt)) break;
                            __builtin_amdgcn_s_sleep(1);
                        }
                        __builtin_amdgcn_fence(__ATOMIC_ACQUIRE, "agent");
                    }
                    __syncthreads();
                }
                const int tc = c + 1;
                float* dst = &inpT[tc & 1][0];
                if (tc < 16) {
                    const float* src = hR + tc * 2048;
                    GLOAD16(src + rw * 256 + lane * 4, dst + rw * 256);
                    GLOAD16(src + (rw + 4) * 256 + lane * 4, dst + (rw + 4) * 256);
                } else if (tc < 18) {
                    const float* src = wT_half + (tc - 16) * 2048;
                    GLOAD16(src + rw * 256 + lane * 4, dst + rw * 256);
                    GLOAD16(src + (rw + 4) * 256 + lane * 4, dst + (rw + 4) * 256);
                } else {
                    const float* src = wT_half + 64 * 64;    // w rows 64..79
                    GLOAD16(src + rw * 256 + lane * 4, dst + rw * 256);
                    if (tid < 192) {                          // x rows 16..18
                        int r = tid >> 6;
                        dst[(16 + r) * 64 + lane] =
                            strokes[(size_t)(half * HB + lane) * (T_ * 3) + t * 3 + r];
                    }
                }
            }
            // ---- compute chunk c: 4b x 4c per thread, K interleaved 4-way ----
            const float* ib = &inpT[c & 1][0];
            const float* wl = &Wl[c * 32 * 16];
            if (c < 18) {
                #pragma unroll
                for (int i = 0; i < 8; ++i) {
                    int k = 4 * i + ks;
                    float4 iv = *(const float4*)(ib + k * 64 + bg44);
                    float4 wv = *(const float4*)(wl + k * 16 + cg4);
                    acc[0][0] = fmaf(iv.x, wv.x, acc[0][0]); acc[0][1] = fmaf(iv.x, wv.y, acc[0][1]);
                    acc[0][2] = fmaf(iv.x, wv.z, acc[0][2]); acc[0][3] = fmaf(iv.x, wv.w, acc[0][3]);
                    acc[1][0] = fmaf(iv.y, wv.x, acc[1][0]); acc[1][1] = fmaf(iv.y, wv.y, acc[1][1]);
                    acc[1][2] = fmaf(iv.y, wv.z, acc[1][2]); acc[1][3] = fmaf(iv.y, wv.w, acc[1][3]);
                    acc[2][0] = fmaf(iv.z, wv.x, acc[2][0]); acc[2][1] = fmaf(iv.z, wv.y, acc[2][1]);
                    acc[2][2] = fmaf(iv.z, wv.z, acc[2][2]); acc[2][3] = fmaf(iv.z, wv.w, acc[2][3]);
                    acc[3][0] = fmaf(iv.w, wv.x, acc[3][0]); acc[3][1] = fmaf(iv.w, wv.y, acc[3][1]);
                    acc[3][2] = fmaf(iv.w, wv.z, acc[3][2]); acc[3][3] = fmaf(iv.w, wv.w, acc[3][3]);
                }
            } else {
                for (int i = 0; i < 5; ++i) {
                    int k = 4 * i + ks;
                    if (k < 19) {
                        float4 iv = *(const float4*)(ib + k * 64 + bg44);
                        float4 wv = *(const float4*)(wl + k * 16 + cg4);
                        acc[0][0] = fmaf(iv.x, wv.x, acc[0][0]); acc[0][1] = fmaf(iv.x, wv.y, acc[0][1]);
                        acc[0][2] = fmaf(iv.x, wv.z, acc[0][2]); acc[0][3] = fmaf(iv.x, wv.w, acc[0][3]);
                        acc[1][0] = fmaf(iv.y, wv.x, acc[1][0]); acc[1][1] = fmaf(iv.y, wv.y, acc[1][1]);
                        acc[1][2] = fmaf(iv.y, wv.z, acc[1][2]); acc[1][3] = fmaf(iv.y, wv.w, acc[1][3]);
                        acc[2][0] = fmaf(iv.z, wv.x, acc[2][0]); acc[2][1] = fmaf(iv.z, wv.y, acc[2][1]);
                        acc[2][2] = fmaf(iv.z, wv.z, acc[2][2]); acc[2][3] = fmaf(iv.z, wv.w, acc[2][3]);
                        acc[3][0] = fmaf(iv.w, wv.x, acc[3][0]); acc[3][1] = fmaf(iv.w, wv.y, acc[3][1]);
                        acc[3][2] = fmaf(iv.w, wv.z, acc[3][2]); acc[3][3] = fmaf(iv.w, wv.w, acc[3][3]);
                    }
                }
            }
            __syncthreads();
        }

        // ---- cross-K reduce (lane bits 4,5) + stash z ----
        #pragma unroll
        for (int bb = 0; bb < 4; ++bb) {
            #pragma unroll
            for (int cc2 = 0; cc2 < 4; ++cc2) {
                float v = acc[bb][cc2];
                v += __shfl_xor(v, 16, 64);
                v += __shfl_xor(v, 32, 64);
                acc[bb][cc2] = v;
            }
            if (ks == 0)
                *(float4*)&zbuf[(bg44 + bb) * 20 + cg4] =
                    make_float4(acc[bb][0], acc[bb][1], acc[bb][2], acc[bb][3]);
        }
        __syncthreads();

        // ---- LSTM pointwise: thread = (b, jl) ----
        {
            int b = tid & 63, jl = tid >> 6;
            int colb = hs * 4 + jl;
            float zi = zbuf[b * 20 + 0  + jl] + bias[colb];
            float zf = zbuf[b * 20 + 4  + jl] + bias[512 + colb];
            float zg = zbuf[b * 20 + 8  + jl] + bias[1024 + colb];
            float zo = zbuf[b * 20 + 12 + jl] + bias[1536 + colb];
            float co = cst[b * 4 + jl];
            float si = 1.f / (1.f + expf(-zi));
            float sf = 1.f / (1.f + expf(-zf));
            float so = 1.f / (1.f + expf(-zo));
            float cn = sf * co + si * tanhf(zg);
            float hn = so * tanhf(cn);
            cst[b * 4 + jl] = cn;
            hW[colb * 64 + b] = hn;                             // [j][b] for GEMM staging
            hT[(size_t)(half * HB + b) * 512 + colb] = hn;      // [b][j] for stage B
        }
        __syncthreads();
        if (tid == 0) stRel(dn_h + hs, (unsigned)(t + 1));       // release h_t (single store)

        // ---- stage B: attention, overlapped with other blocks' next GEMM ----
        if (isB) {
            if (tid < 64) {                // wait ALL h_t of this half
                const unsigned tgt = (unsigned)(t + 1);
                for (;;) {
                    unsigned v0 = ldA(dn_h + tid);
                    unsigned v1 = ldA(dn_h + 64 + tid);
                    if (!__any((v0 < tgt) | (v1 < tgt))) break;
                    __builtin_amdgcn_s_sleep(1);
                }
                __builtin_amdgcn_fence(__ATOMIC_ACQUIRE, "agent");
            }
            __syncthreads();
            if (tid < 128)   // coalesced 2KB h-column load
                ((float4*)zbuf)[tid] = ((const float4*)(hT + (size_t)bB * 512))[tid];
            __syncthreads();
            if (tid < 240) {                       // y = h @ Wd : 30 cols x 8 segs
                int col = tid >> 3, seg = tid & 7;
                const float* hp = zbuf + seg * 64;
                const float* wdp = Wd + (size_t)seg * 64 * 30 + col;
                float s = 0.f;
                #pragma unroll 8
                for (int jj = 0; jj < 64; ++jj) s = fmaf(hp[jj], wdp[jj * 30], s);
                s += __shfl_down(s, 4, 8);
                s += __shfl_down(s, 2, 8);
                s += __shfl_down(s, 1, 8);
                if (seg == 0) yl[col] = s;
            }
            __syncthreads();
            if (tid < 30) {
                float e = expf(yl[tid] + bd[tid]);
                yl[tid] = e;
                if (tid >= 20) kap[tid - 20] += e;
            }
            __syncthreads();
            if (tid <= U_) {
                float u = (float)tid, s = 0.f;
                #pragma unroll
                for (int m = 0; m < M_; ++m) {
                    float d = kap[m] - u;
                    s += yl[m] * expf(-yl[10 + m] * d * d);
                }
                wf[tid] = s;
            }
            __syncthreads();
            float* op = out + ((size_t)bB * T_ + t) * 593;
            if (tid < 64) {                        // barrier-free in-wave argmax tournament
                float v = wf[tid]; int ii = tid;   // (same bracket + strict-> tie rule)
                float v2 = wf[tid + 64];
                if (v2 > v) { v = v2; ii = tid + 64; }
                #pragma unroll
                for (int s2 = 32; s2 >= 1; s2 >>= 1) {
                    float ov = __shfl_down(v, s2, 64);
                    int   oi = __shfl_down(ii, s2, 64);
                    if (ov > v) { v = ov; ii = oi; }
                }
                if (tid == 0) {
                    if (wf[128] > v) ii = 128;     // fold index 128 (strict >)
                    op[592] = (float)ii;
                }
            }
            for (int j = tid; j < H_; j += NTHR) op[j] = zbuf[j];   // coalesced h out
            if (tid < N_) {                        // w = wfull[:128] @ trans[b]
                const float* tp = trans + (size_t)bB * (U_ * N_) + tid;
                float s = 0.f;
                #pragma unroll 4
                for (int u = 0; u < U_; ++u) s = fmaf(wf[u], tp[u * N_], s);
                op[512 + tid] = s;
                wT_half[tid * 64 + (bB & 63)] = s;
            }
            __syncthreads();
            if (tid == 0) stRel(dn_w + (hs >> 1), (unsigned)(t + 1));   // release w_t
        }
    }
}

extern "C" void kernel_launch(void* const* d_in, const int* in_sizes, int n_in,
                              void* d_out, int out_size, void* d_ws, size_t ws_size,
                              hipStream_t stream) {
    const float* strokes = (const float*)d_in[0];
    const float* trans   = (const float*)d_in[1];
    // d_in[2] = enumerated (arange, recomputed in-kernel)
    const float* Wx      = (const float*)d_in[3];
    const float* Wh      = (const float*)d_in[4];
    const float* bias    = (const float*)d_in[5];
    const float* Wd      = (const float*)d_in[6];
    const float* bd      = (const float*)d_in[7];
    float* out = (float*)d_out;

    unsigned* cnt = (unsigned*)d_ws;                       // 4 KB: [128]=init, [256..511]=dn_h, [512..639]=dn_w
    float* hbuf  = (float*)((char*)d_ws + 4096);           // [par][half][512][64] 512 KB
    float* wbufT = hbuf + 2 * 2 * H_ * HB;                 // [half][80][64] 40 KB
    float* hT    = wbufT + 2 * N_ * HB;                    // [128][512] 256 KB

    hipMemsetAsync(d_ws, 0, 4096, stream);                 // reset counters/slots (ws is poisoned)
    hipLaunchKernelGGL(rnn_kernel, dim3(NBLK), dim3(NTHR), 0, stream,
                       strokes, trans, Wx, Wh, bias, Wd, bd, out, hbuf, wbufT, hT, cnt);
}

// Round 3
// 20201.291 us; speedup vs baseline: 3.1227x; 1.1235x over previous
//
#include <hip/hip_runtime.h>
#include <math.h>

#define NBLK 256
#define NTHR 256
#define HB 64      // batches per half
#define T_ 512
#define U_ 128
#define N_ 80
#define H_ 512
#define M_ 10
#define KTOT 595   // K order: [h 0..511][w 0..79][x 0..2]

typedef __attribute__((address_space(1))) const unsigned int* gp1_t;
typedef __attribute__((address_space(3))) unsigned int* lp3_t;
// width-16 global->LDS DMA: lane i writes ldsbase + i*16, reads gptr + i*16
#define GLOAD16(gp, lp) __builtin_amdgcn_global_load_lds((gp1_t)(gp), (lp3_t)(lp), 16, 0, 0)

__device__ __forceinline__ unsigned ldA(const unsigned* p) {
    return __hip_atomic_load(p, __ATOMIC_RELAXED, __HIP_MEMORY_SCOPE_AGENT);
}
__device__ __forceinline__ void stRel(unsigned* p, unsigned v) {
    __hip_atomic_store(p, v, __ATOMIC_RELEASE, __HIP_MEMORY_SCOPE_AGENT);
}

__global__ __launch_bounds__(NTHR) void rnn_kernel(
    const float* __restrict__ strokes, const float* __restrict__ trans,
    const float* __restrict__ Wx, const float* __restrict__ Wh,
    const float* __restrict__ bias, const float* __restrict__ Wd,
    const float* __restrict__ bd, float* __restrict__ out,
    float* __restrict__ hbuf, float* __restrict__ wbufT, float* __restrict__ hT,
    unsigned* __restrict__ cnt) {

    // LDS ~62 KB (<64 KB static)
    __shared__ __align__(16) float Wl[KTOT * 16];      // 38080 B weight slice, permuted K order
    __shared__ __align__(16) float inpT[2][32 * 64];   // 16384 B dbuf input chunks [k][b]
    __shared__ __align__(16) float zbuf[64 * 20];      // 5120 B z / reused as h-column in stage B
    __shared__ float cst[256];                         // c-state [b][jl]
    __shared__ float kap[M_];
    __shared__ float yl[30];
    __shared__ float wf[U_ + 1];
    __shared__ float wpart[160];                       // w partial sums [seg][n]

    const int tid  = threadIdx.x;
    const int bid  = blockIdx.x;
    const int half = bid >> 7;     // batch half
    const int hs   = bid & 127;    // h-slice: h-units hs*4..hs*4+3
    const int lane = tid & 63;
    const int rw   = tid >> 6;     // wave id = col-group (gate)
    const int bg4  = lane & 15;    // batch group of 4
    const int ks   = lane >> 4;    // K-split 4 (lane bits 4-5)
    const int cg4  = rw * 4;
    const int bg44 = bg4 * 4;

    // per-block done-slots (no RMW fan-in): dn_h[half][128], dn_w[half][64]
    unsigned* dn_h = cnt + 256 + half * 128;
    unsigned* dn_w = cnt + 512 + half * 64;
    float* wT_half = wbufT + half * (N_ * HB);

    const bool isB = (hs & 1) == 0;                    // 64 stage-B blocks per half
    const int  bB  = half * HB + (hs >> 1);            // its batch

    // ---- register-resident stage-B weights (read-only; dodge per-step L2 inval) ----
    float trW[64];   // Wd slice: thread tid<240: col=tid>>3, seg=tid&7, trW[j]=Wd[(seg*64+j)*30+col]
    float trT[64];   // trans slice: thread tid<160: s2=(tid>=80), n=tid-80*s2, trT[j]=trans[bB][s2*64+j][n]
    #pragma unroll
    for (int j = 0; j < 64; ++j) { trW[j] = 0.f; trT[j] = 0.f; }
    if (isB) {
        if (tid < 240) {
            const int col = tid >> 3, seg = tid & 7;
            const float* wdp = Wd + (size_t)seg * 64 * 30 + col;
            #pragma unroll
            for (int j = 0; j < 64; ++j) trW[j] = wdp[j * 30];
        }
        if (tid < 160) {
            const int s2 = (tid >= 80) ? 1 : 0;
            const int n  = tid - 80 * s2;
            const float* tp = trans + (size_t)bB * (U_ * N_) + (size_t)(s2 * 64) * N_ + n;
            #pragma unroll
            for (int j = 0; j < 64; ++j) trT[j] = tp[j * N_];
        }
    }

    // ---- init: weights (permuted K), zero state ----
    for (int idx = tid; idx < KTOT * 16; idx += NTHR) {
        int kk = idx >> 4, cc = idx & 15;
        int col = (cc >> 2) * 512 + hs * 4 + (cc & 3);   // gate*512 + h-unit
        float v;
        if (kk < 512)      v = Wh[kk * 2048 + col];
        else if (kk < 592) v = Wx[(3 + kk - 512) * 2048 + col];
        else               v = Wx[(kk - 592) * 2048 + col];
        Wl[idx] = v;
    }
    for (int i = tid; i < 256; i += NTHR) cst[i] = 0.f;
    if (tid < M_) kap[tid] = 0.f;
    for (int i = bid * NTHR + tid; i < 2 * H_ * HB + 2 * N_ * HB; i += NBLK * NTHR) {
        if (i < 2 * H_ * HB) hbuf[i] = 0.f;            // parity-0 h = 0
        else wbufT[i - 2 * H_ * HB] = 0.f;             // w_{-1} = 0
    }
    __syncthreads();
    if (tid == 0) {                                    // one-time flat init barrier
        __threadfence();
        atomicAdd(&cnt[128], 1u);
        while (__hip_atomic_load(&cnt[128], __ATOMIC_RELAXED, __HIP_MEMORY_SCOPE_AGENT) < (unsigned)NBLK)
            __builtin_amdgcn_s_sleep(1);
        __threadfence();
    }
    __syncthreads();

    for (int t = 0; t < T_; ++t) {
        const float* hR = hbuf + ((t & 1) * 2 + half) * (H_ * HB);
        float*       hW = hbuf + (((t + 1) & 1) * 2 + half) * (H_ * HB);

        // ---- wait h_{t-1}: all 128 producer blocks of this half at step >= t ----
        if (tid < 64) {
            const unsigned tgt = (unsigned)t;
            for (;;) {
                unsigned v0 = ldA(dn_h + tid);
                unsigned v1 = ldA(dn_h + 64 + tid);
                if (!__any((v0 < tgt) | (v1 < tgt))) break;
                __builtin_amdgcn_s_sleep(1);
            }
            __builtin_amdgcn_fence(__ATOMIC_ACQUIRE, "agent");
        }
        __syncthreads();

        // prefetch this step's stroke values into regs (consumed at chunk-18 staging,
        // ~15 chunks later -> LLC latency fully hidden, no mid-GEMM RTT)
        float xpre = 0.f;
        if (tid < 192)
            xpre = strokes[(size_t)(half * HB + lane) * (T_ * 3) + t * 3 + (tid >> 6)];

        float acc[4][4];
        #pragma unroll
        for (int a = 0; a < 4; ++a)
            #pragma unroll
            for (int b2 = 0; b2 < 4; ++b2) acc[a][b2] = 0.f;

        // stage chunk 0 (h rows 0..31): 2 DMA issues per wave, 4 rows each
        {
            const float* src = hR;
            float* dst = &inpT[0][0];
            GLOAD16(src + rw * 256 + lane * 4, dst + rw * 256);
            GLOAD16(src + (rw + 4) * 256 + lane * 4, dst + (rw + 4) * 256);
        }
        __syncthreads();

        for (int c = 0; c < 19; ++c) {
            if (c + 1 < 19) {
                if (c + 1 == 16) {        // w rows start: need w_{t-1}
                    if (tid < 64) {
                        const unsigned tgt = (unsigned)t;
                        for (;;) {
                            unsigned v0 = ldA(dn_w + tid);
                            if (!__any(v0 < tgt)) break;
                            __builtin_amdgcn_s_sleep(1);
                        }
                        __builtin_amdgcn_fence(__ATOMIC_ACQUIRE, "agent");
                    }
                    __syncthreads();
                }
                const int tc = c + 1;
                float* dst = &inpT[tc & 1][0];
                if (tc < 16) {
                    const float* src = hR + tc * 2048;
                    GLOAD16(src + rw * 256 + lane * 4, dst + rw * 256);
                    GLOAD16(src + (rw + 4) * 256 + lane * 4, dst + (rw + 4) * 256);
                } else if (tc < 18) {
                    const float* src = wT_half + (tc - 16) * 2048;
                    GLOAD16(src + rw * 256 + lane * 4, dst + rw * 256);
                    GLOAD16(src + (rw + 4) * 256 + lane * 4, dst + (rw + 4) * 256);
                } else {
                    const float* src = wT_half + 64 * 64;    // w rows 64..79
                    GLOAD16(src + rw * 256 + lane * 4, dst + rw * 256);
                    if (tid < 192) {                          // x rows 16..18 (prefetched)
                        dst[(16 + (tid >> 6)) * 64 + lane] = xpre;
                    }
                }
            }
            // ---- compute chunk c: 4b x 4c per thread, K interleaved 4-way ----
            const float* ib = &inpT[c & 1][0];
            const float* wl = &Wl[c * 32 * 16];
            if (c < 18) {
                #pragma unroll
                for (int i = 0; i < 8; ++i) {
                    int k = 4 * i + ks;
                    float4 iv = *(const float4*)(ib + k * 64 + bg44);
                    float4 wv = *(const float4*)(wl + k * 16 + cg4);
                    acc[0][0] = fmaf(iv.x, wv.x, acc[0][0]); acc[0][1] = fmaf(iv.x, wv.y, acc[0][1]);
                    acc[0][2] = fmaf(iv.x, wv.z, acc[0][2]); acc[0][3] = fmaf(iv.x, wv.w, acc[0][3]);
                    acc[1][0] = fmaf(iv.y, wv.x, acc[1][0]); acc[1][1] = fmaf(iv.y, wv.y, acc[1][1]);
                    acc[1][2] = fmaf(iv.y, wv.z, acc[1][2]); acc[1][3] = fmaf(iv.y, wv.w, acc[1][3]);
                    acc[2][0] = fmaf(iv.z, wv.x, acc[2][0]); acc[2][1] = fmaf(iv.z, wv.y, acc[2][1]);
                    acc[2][2] = fmaf(iv.z, wv.z, acc[2][2]); acc[2][3] = fmaf(iv.z, wv.w, acc[2][3]);
                    acc[3][0] = fmaf(iv.w, wv.x, acc[3][0]); acc[3][1] = fmaf(iv.w, wv.y, acc[3][1]);
                    acc[3][2] = fmaf(iv.w, wv.z, acc[3][2]); acc[3][3] = fmaf(iv.w, wv.w, acc[3][3]);
                }
            } else {
                for (int i = 0; i < 5; ++i) {
                    int k = 4 * i + ks;
                    if (k < 19) {
                        float4 iv = *(const float4*)(ib + k * 64 + bg44);
                        float4 wv = *(const float4*)(wl + k * 16 + cg4);
                        acc[0][0] = fmaf(iv.x, wv.x, acc[0][0]); acc[0][1] = fmaf(iv.x, wv.y, acc[0][1]);
                        acc[0][2] = fmaf(iv.x, wv.z, acc[0][2]); acc[0][3] = fmaf(iv.x, wv.w, acc[0][3]);
                        acc[1][0] = fmaf(iv.y, wv.x, acc[1][0]); acc[1][1] = fmaf(iv.y, wv.y, acc[1][1]);
                        acc[1][2] = fmaf(iv.y, wv.z, acc[1][2]); acc[1][3] = fmaf(iv.y, wv.w, acc[1][3]);
                        acc[2][0] = fmaf(iv.z, wv.x, acc[2][0]); acc[2][1] = fmaf(iv.z, wv.y, acc[2][1]);
                        acc[2][2] = fmaf(iv.z, wv.z, acc[2][2]); acc[2][3] = fmaf(iv.z, wv.w, acc[2][3]);
                        acc[3][0] = fmaf(iv.w, wv.x, acc[3][0]); acc[3][1] = fmaf(iv.w, wv.y, acc[3][1]);
                        acc[3][2] = fmaf(iv.w, wv.z, acc[3][2]); acc[3][3] = fmaf(iv.w, wv.w, acc[3][3]);
                    }
                }
            }
            __syncthreads();
        }

        // ---- cross-K reduce (lane bits 4,5) + stash z ----
        #pragma unroll
        for (int bb = 0; bb < 4; ++bb) {
            #pragma unroll
            for (int cc2 = 0; cc2 < 4; ++cc2) {
                float v = acc[bb][cc2];
                v += __shfl_xor(v, 16, 64);
                v += __shfl_xor(v, 32, 64);
                acc[bb][cc2] = v;
            }
            if (ks == 0)
                *(float4*)&zbuf[(bg44 + bb) * 20 + cg4] =
                    make_float4(acc[bb][0], acc[bb][1], acc[bb][2], acc[bb][3]);
        }
        __syncthreads();

        // ---- LSTM pointwise: thread = (b, jl) ----
        {
            int b = tid & 63, jl = tid >> 6;
            int colb = hs * 4 + jl;
            float zi = zbuf[b * 20 + 0  + jl] + bias[colb];
            float zf = zbuf[b * 20 + 4  + jl] + bias[512 + colb];
            float zg = zbuf[b * 20 + 8  + jl] + bias[1024 + colb];
            float zo = zbuf[b * 20 + 12 + jl] + bias[1536 + colb];
            float co = cst[b * 4 + jl];
            float si = 1.f / (1.f + expf(-zi));
            float sf = 1.f / (1.f + expf(-zf));
            float so = 1.f / (1.f + expf(-zo));
            float cn = sf * co + si * tanhf(zg);
            float hn = so * tanhf(cn);
            cst[b * 4 + jl] = cn;
            hW[colb * 64 + b] = hn;                             // [j][b] for GEMM staging
            hT[(size_t)(half * HB + b) * 512 + colb] = hn;      // [b][j] for stage B
        }
        __syncthreads();
        if (tid == 0) stRel(dn_h + hs, (unsigned)(t + 1));       // release h_t (single store)

        // ---- stage B: attention, overlapped with other blocks' next GEMM ----
        if (isB) {
            if (tid < 64) {                // wait ALL h_t of this half
                const unsigned tgt = (unsigned)(t + 1);
                for (;;) {
                    unsigned v0 = ldA(dn_h + tid);
                    unsigned v1 = ldA(dn_h + 64 + tid);
                    if (!__any((v0 < tgt) | (v1 < tgt))) break;
                    __builtin_amdgcn_s_sleep(1);
                }
                __builtin_amdgcn_fence(__ATOMIC_ACQUIRE, "agent");
            }
            __syncthreads();
            if (tid < 128)   // coalesced 2KB h-column load
                ((float4*)zbuf)[tid] = ((const float4*)(hT + (size_t)bB * 512))[tid];
            __syncthreads();
            if (tid < 240) {                       // y = h @ Wd from registers
                int seg = tid & 7;
                const float* hp = zbuf + seg * 64;
                float s = 0.f;
                #pragma unroll
                for (int jj = 0; jj < 64; ++jj) s = fmaf(hp[jj], trW[jj], s);
                s += __shfl_down(s, 4, 8);
                s += __shfl_down(s, 2, 8);
                s += __shfl_down(s, 1, 8);
                if (seg == 0) yl[tid >> 3] = s;
            }
            __syncthreads();
            if (tid < 30) {
                float e = expf(yl[tid] + bd[tid]);
                yl[tid] = e;
                if (tid >= 20) kap[tid - 20] += e;
            }
            __syncthreads();
            if (tid <= U_) {
                float u = (float)tid, s = 0.f;
                #pragma unroll
                for (int m = 0; m < M_; ++m) {
                    float d = kap[m] - u;
                    s += yl[m] * expf(-yl[10 + m] * d * d);
                }
                wf[tid] = s;
            }
            __syncthreads();
            // w = wfull[:128] @ trans[b] from registers: 2 ordered 64-term segments
            if (tid < 160) {
                const int s2 = (tid >= 80) ? 1 : 0;
                const int n  = tid - 80 * s2;
                const float* wp = wf + s2 * 64;
                float s = 0.f;
                #pragma unroll
                for (int u = 0; u < 64; ++u) s = fmaf(wp[u], trT[u], s);
                wpart[s2 * 80 + n] = s;
            }
            __syncthreads();
            float* op = out + ((size_t)bB * T_ + t) * 593;
            if (tid < N_) {
                float s = wpart[tid] + wpart[80 + tid];
                op[512 + tid] = s;
                wT_half[tid * 64 + (bB & 63)] = s;
            }
            __syncthreads();
            if (tid == 0) stRel(dn_w + (hs >> 1), (unsigned)(t + 1));   // release w_t EARLY

            // non-critical tail (consumers already unblocked)
            if (tid < 64) {                        // barrier-free in-wave argmax tournament
                float v = wf[tid]; int ii = tid;   // (same bracket + strict-> tie rule)
                float v2 = wf[tid + 64];
                if (v2 > v) { v = v2; ii = tid + 64; }
                #pragma unroll
                for (int s2 = 32; s2 >= 1; s2 >>= 1) {
                    float ov = __shfl_down(v, s2, 64);
                    int   oi = __shfl_down(ii, s2, 64);
                    if (ov > v) { v = ov; ii = oi; }
                }
                if (tid == 0) {
                    if (wf[128] > v) ii = 128;     // fold index 128 (strict >)
                    op[592] = (float)ii;
                }
            }
            for (int j = tid; j < H_; j += NTHR) op[j] = zbuf[j];   // coalesced h out
        }
    }
}

extern "C" void kernel_launch(void* const* d_in, const int* in_sizes, int n_in,
                              void* d_out, int out_size, void* d_ws, size_t ws_size,
                              hipStream_t stream) {
    const float* strokes = (const float*)d_in[0];
    const float* trans   = (const float*)d_in[1];
    // d_in[2] = enumerated (arange, recomputed in-kernel)
    const float* Wx      = (const float*)d_in[3];
    const float* Wh      = (const float*)d_in[4];
    const float* bias    = (const float*)d_in[5];
    const float* Wd      = (const float*)d_in[6];
    const float* bd      = (const float*)d_in[7];
    float* out = (float*)d_out;

    unsigned* cnt = (unsigned*)d_ws;                       // 4 KB: [128]=init, [256..511]=dn_h, [512..639]=dn_w
    float* hbuf  = (float*)((char*)d_ws + 4096);           // [par][half][512][64] 512 KB
    float* wbufT = hbuf + 2 * 2 * H_ * HB;                 // [half][80][64] 40 KB
    float* hT    = wbufT + 2 * N_ * HB;                    // [128][512] 256 KB

    hipMemsetAsync(d_ws, 0, 4096, stream);                 // reset counters/slots (ws is poisoned)
    hipLaunchKernelGGL(rnn_kernel, dim3(NBLK), dim3(NTHR), 0, stream,
                       strokes, trans, Wx, Wh, bias, Wd, bd, out, hbuf, wbufT, hT, cnt);
}